// Round 2
// baseline (15.854 us; speedup 1.0000x reference)
//
#include <hip/hip_runtime.h>
#include <hip/hip_bf16.h>

// out[bt][s][d] = W_T[text[bt][s]][d] + b[d] + pe[s][d]
// B=4, S=2048, D=1024, VOCAB=50257. All f32 except text (int32).
// 4 tokens per block (grid 2048), 256 threads, float4 per thread per token.
// 8 independent 16B loads in flight per lane -> latency-hiding via ILP,
// fewer blocks -> less scheduling overhead.

#define D_MODEL 1024
#define D4 (D_MODEL / 4)   // 256
#define SEQ 2048
#define TPB 4              // tokens per block

__global__ __launch_bounds__(256) void embed_kernel(
    const int* __restrict__ text,      // [8192]
    const float4* __restrict__ W_T,    // [50257][256]
    const float4* __restrict__ bias,   // [256]
    const float4* __restrict__ pe,     // [4096][256] (use first 2048 rows)
    float4* __restrict__ out)          // [8192][256]
{
    const int d4   = threadIdx.x;          // 0..255
    const int base = blockIdx.x * TPB;     // first token of this block

    const float4 bb = bias[d4];

    int rows[TPB];
    #pragma unroll
    for (int t = 0; t < TPB; ++t)
        rows[t] = text[base + t];          // block-uniform -> scalar loads

    float4 w[TPB];
    #pragma unroll
    for (int t = 0; t < TPB; ++t)
        w[t] = W_T[(size_t)rows[t] * D4 + d4];

    float4 p[TPB];
    #pragma unroll
    for (int t = 0; t < TPB; ++t)
        p[t] = pe[(size_t)((base + t) & (SEQ - 1)) * D4 + d4];

    #pragma unroll
    for (int t = 0; t < TPB; ++t) {
        float4 o;
        o.x = w[t].x + bb.x + p[t].x;
        o.y = w[t].y + bb.y + p[t].y;
        o.z = w[t].z + bb.z + p[t].z;
        o.w = w[t].w + bb.w + p[t].w;
        out[(size_t)(base + t) * D4 + d4] = o;
    }
}

extern "C" void kernel_launch(void* const* d_in, const int* in_sizes, int n_in,
                              void* d_out, int out_size, void* d_ws, size_t ws_size,
                              hipStream_t stream) {
    const int*    text = (const int*)d_in[0];      // [4*2048]
    const float4* W_T  = (const float4*)d_in[1];   // [50257*1024] f32
    const float4* bias = (const float4*)d_in[2];   // [1024] f32
    const float4* pe   = (const float4*)d_in[3];   // [1*4096*1024] f32
    float4* out = (float4*)d_out;

    const int n_tokens = in_sizes[0];              // 8192
    embed_kernel<<<n_tokens / TPB, 256, 0, stream>>>(text, W_T, bias, pe, out);
}